// Round 1
// baseline (102.886 us; speedup 1.0000x reference)
//
#include <hip/hip_runtime.h>

#define TPB 256
#define PTS 4
#define CH  512

// ---------------------------------------------------------------------------
// init: fill min-bits arrays with +inf bit pattern, zero the output scalar
// ---------------------------------------------------------------------------
__global__ void init_kernel(unsigned* __restrict__ minb, int n, float* __restrict__ out) {
    int i = blockIdx.x * blockDim.x + threadIdx.x;
    if (i < n) minb[i] = 0x7f800000u;   // +inf
    if (i == 0) out[0] = 0.0f;
}

// ---------------------------------------------------------------------------
// minpass: for each query point (b,n) compute min over a slice of db points of
// the squared Euclidean distance; combine slices via atomicMin on float bits
// (valid: squared distances are non-negative, so uint order == float order).
// q:  [B, nq, 3]  db: [B, ndb, 3]  minbits: [B*nq]
// grid: (B * nq/(TPB*PTS), nsplit)
// ---------------------------------------------------------------------------
__global__ void __launch_bounds__(TPB) minpass(
    const float* __restrict__ q, const float* __restrict__ db,
    unsigned* __restrict__ minbits, int nq, int ndb, int nsplit)
{
    __shared__ float sx[CH], sy[CH], sz[CH];

    const int tilesPerB = nq / (TPB * PTS);
    const int b    = blockIdx.x / tilesPerB;
    const int tile = blockIdx.x % tilesPerB;
    const int nbase = tile * (TPB * PTS) + threadIdx.x;

    float px[PTS], py[PTS], pz[PTS], mn[PTS];
#pragma unroll
    for (int p = 0; p < PTS; ++p) {
        const int n = nbase + p * TPB;
        const float* qp = q + ((size_t)b * nq + n) * 3;
        px[p] = qp[0]; py[p] = qp[1]; pz[p] = qp[2];
        mn[p] = 3.4e38f;
    }

    const int dbPer   = ndb / nsplit;
    const int dbStart = blockIdx.y * dbPer;

    for (int c0 = 0; c0 < dbPer; c0 += CH) {
        // cooperative stage of CH db points into LDS (SoA)
        for (int i = threadIdx.x; i < CH; i += TPB) {
            const float* dp = db + ((size_t)b * ndb + dbStart + c0 + i) * 3;
            sx[i] = dp[0]; sy[i] = dp[1]; sz[i] = dp[2];
        }
        __syncthreads();

#pragma unroll 4
        for (int j = 0; j < CH; ++j) {
            const float tx = sx[j], ty = sy[j], tz = sz[j];  // broadcast reads
#pragma unroll
            for (int p = 0; p < PTS; ++p) {
                const float dx = px[p] - tx;
                const float dy = py[p] - ty;
                const float dz = pz[p] - tz;
                const float d2 = fmaf(dx, dx, fmaf(dy, dy, dz * dz));
                mn[p] = fminf(mn[p], d2);
            }
        }
        __syncthreads();
    }

#pragma unroll
    for (int p = 0; p < PTS; ++p) {
        atomicMin(&minbits[(size_t)b * nq + nbase + p * TPB], __float_as_uint(mn[p]));
    }
}

// ---------------------------------------------------------------------------
// finalize: out = sum(sqrt(m1))/(B*N) + sum(sqrt(m2))/(B*M)
// single block -> deterministic
// ---------------------------------------------------------------------------
__global__ void __launch_bounds__(1024) finalize(
    const unsigned* __restrict__ m1, const unsigned* __restrict__ m2,
    int n1, int n2, float inv1, float inv2, float* __restrict__ out)
{
    __shared__ float red[1024];
    float s = 0.0f;
    for (int i = threadIdx.x; i < n1; i += 1024) s += sqrtf(__uint_as_float(m1[i])) * inv1;
    for (int i = threadIdx.x; i < n2; i += 1024) s += sqrtf(__uint_as_float(m2[i])) * inv2;
    red[threadIdx.x] = s;
    __syncthreads();
    for (int off = 512; off > 0; off >>= 1) {
        if (threadIdx.x < off) red[threadIdx.x] += red[threadIdx.x + off];
        __syncthreads();
    }
    if (threadIdx.x == 0) out[0] = red[0];
}

// ---------------------------------------------------------------------------
extern "C" void kernel_launch(void* const* d_in, const int* in_sizes, int n_in,
                              void* d_out, int out_size, void* d_ws, size_t ws_size,
                              hipStream_t stream) {
    const float* pred   = (const float*)d_in[0];   // [B,N,3]
    const float* target = (const float*)d_in[1];   // [B,M,3]
    float* out = (float*)d_out;

    const int B = 4, N = 8192, M = 8192;

    unsigned* m1 = (unsigned*)d_ws;                 // [B*N]
    unsigned* m2 = m1 + (size_t)B * N;              // [B*M]

    const int tot = B * (N + M);
    init_kernel<<<(tot + 255) / 256, 256, 0, stream>>>(m1, tot, out);

    const int NSPLIT = 16;
    dim3 g1(B * N / (TPB * PTS), NSPLIT);
    minpass<<<g1, TPB, 0, stream>>>(pred, target, m1, N, M, NSPLIT);

    dim3 g2(B * M / (TPB * PTS), NSPLIT);
    minpass<<<g2, TPB, 0, stream>>>(target, pred, m2, M, N, NSPLIT);

    finalize<<<1, 1024, 0, stream>>>(m1, m2, B * N, B * M,
                                     1.0f / (B * N), 1.0f / (B * M), out);
}

// Round 2
// 72.914 us; speedup vs baseline: 1.4110x; 1.4110x over previous
//
#include <hip/hip_runtime.h>

#define TPB 256
#define PTS 4
#define CH  512
#define NSPLIT 16

// ---------------------------------------------------------------------------
// init: fill min-bits arrays with +inf bit pattern, zero the output scalar
// ---------------------------------------------------------------------------
__global__ void init_kernel(unsigned* __restrict__ minb, int n, float* __restrict__ out) {
    int i = blockIdx.x * blockDim.x + threadIdx.x;
    if (i < n) minb[i] = 0x7f800000u;   // +inf
    if (i == 0) out[0] = 0.0f;
}

// ---------------------------------------------------------------------------
// minpass: expansion form. For query p and db point t:
//   d2 = |p|^2 + (|t|^2 - 2 p.t)
// We minimize e = |t|^2 - 2 p.t  (|p|^2 is a constant shift per query),
// staging per db point the float4 (-2tx, -2ty, -2tz, |t|^2) in LDS.
// Inner loop: 3 fma + 1 min per pair, one broadcast ds_read_b128 per point.
// blockIdx.z selects pass (0: pred->target, 1: target->pred).
// Combine db-splits via atomicMin on float bits (non-negative after clamp).
// ---------------------------------------------------------------------------
__global__ void __launch_bounds__(TPB) minpass(
    const float* __restrict__ pred, const float* __restrict__ target,
    unsigned* __restrict__ m1, unsigned* __restrict__ m2,
    int N, int M)
{
    const int pass = blockIdx.z;
    const float* __restrict__ q  = pass ? target : pred;
    const float* __restrict__ db = pass ? pred   : target;
    unsigned* __restrict__ minbits = pass ? m2 : m1;
    const int nq  = pass ? M : N;
    const int ndb = pass ? N : M;

    __shared__ float4 st[CH];

    const int tilesPerB = nq / (TPB * PTS);
    const int b    = blockIdx.x / tilesPerB;
    const int tile = blockIdx.x % tilesPerB;
    const int nbase = tile * (TPB * PTS) + threadIdx.x;

    float px[PTS], py[PTS], pz[PTS], xn[PTS], mnA[PTS], mnB[PTS];
#pragma unroll
    for (int p = 0; p < PTS; ++p) {
        const float* qp = q + ((size_t)b * nq + nbase + p * TPB) * 3;
        px[p] = qp[0]; py[p] = qp[1]; pz[p] = qp[2];
        xn[p] = fmaf(px[p], px[p], fmaf(py[p], py[p], pz[p] * pz[p]));
        mnA[p] = 3.4e38f; mnB[p] = 3.4e38f;
    }

    const int dbPer   = ndb / NSPLIT;
    const int dbStart = blockIdx.y * dbPer;

    for (int c0 = 0; c0 < dbPer; c0 += CH) {
        // stage CH db points as (-2x, -2y, -2z, |t|^2)
        for (int i = threadIdx.x; i < CH; i += TPB) {
            const float* dp = db + ((size_t)b * ndb + dbStart + c0 + i) * 3;
            const float tx = dp[0], ty = dp[1], tz = dp[2];
            st[i] = make_float4(-2.0f * tx, -2.0f * ty, -2.0f * tz,
                                fmaf(tx, tx, fmaf(ty, ty, tz * tz)));
        }
        __syncthreads();

#pragma unroll 4
        for (int j = 0; j < CH; j += 2) {
            const float4 ta = st[j];
            const float4 tb = st[j + 1];
#pragma unroll
            for (int p = 0; p < PTS; ++p) {
                float ea = fmaf(pz[p], ta.z, ta.w);
                float eb = fmaf(pz[p], tb.z, tb.w);
                ea = fmaf(py[p], ta.y, ea);
                eb = fmaf(py[p], tb.y, eb);
                ea = fmaf(px[p], ta.x, ea);
                eb = fmaf(px[p], tb.x, eb);
                mnA[p] = fminf(mnA[p], ea);
                mnB[p] = fminf(mnB[p], eb);
            }
        }
        __syncthreads();
    }

#pragma unroll
    for (int p = 0; p < PTS; ++p) {
        const float d2 = fmaxf(xn[p] + fminf(mnA[p], mnB[p]), 0.0f);
        atomicMin(&minbits[(size_t)b * nq + nbase + p * TPB], __float_as_uint(d2));
    }
}

// ---------------------------------------------------------------------------
// finalize: out = sum(sqrt(m1))/(B*N) + sum(sqrt(m2))/(B*M)
// single block -> deterministic
// ---------------------------------------------------------------------------
__global__ void __launch_bounds__(1024) finalize(
    const unsigned* __restrict__ m1, const unsigned* __restrict__ m2,
    int n1, int n2, float inv1, float inv2, float* __restrict__ out)
{
    __shared__ float red[1024];
    float s = 0.0f;
    for (int i = threadIdx.x; i < n1; i += 1024) s += sqrtf(__uint_as_float(m1[i])) * inv1;
    for (int i = threadIdx.x; i < n2; i += 1024) s += sqrtf(__uint_as_float(m2[i])) * inv2;
    red[threadIdx.x] = s;
    __syncthreads();
    for (int off = 512; off > 0; off >>= 1) {
        if (threadIdx.x < off) red[threadIdx.x] += red[threadIdx.x + off];
        __syncthreads();
    }
    if (threadIdx.x == 0) out[0] = red[0];
}

// ---------------------------------------------------------------------------
extern "C" void kernel_launch(void* const* d_in, const int* in_sizes, int n_in,
                              void* d_out, int out_size, void* d_ws, size_t ws_size,
                              hipStream_t stream) {
    const float* pred   = (const float*)d_in[0];   // [B,N,3]
    const float* target = (const float*)d_in[1];   // [B,M,3]
    float* out = (float*)d_out;

    const int B = 4, N = 8192, M = 8192;

    unsigned* m1 = (unsigned*)d_ws;                 // [B*N]
    unsigned* m2 = m1 + (size_t)B * N;              // [B*M]

    const int tot = B * (N + M);
    init_kernel<<<(tot + 255) / 256, 256, 0, stream>>>(m1, tot, out);

    dim3 g(B * N / (TPB * PTS), NSPLIT, 2);
    minpass<<<g, TPB, 0, stream>>>(pred, target, m1, m2, N, M);

    finalize<<<1, 1024, 0, stream>>>(m1, m2, B * N, B * M,
                                     1.0f / (B * N), 1.0f / (B * M), out);
}

// Round 3
// 53.672 us; speedup vs baseline: 1.9169x; 1.3585x over previous
//
#include <hip/hip_runtime.h>

typedef float v2f __attribute__((ext_vector_type(2)));
typedef float v4f __attribute__((ext_vector_type(4)));

#define TPB 256
#define PTS 16              // queries per thread
#define QP  (PTS/2)         // packed query pairs
#define NSPLIT 32
#define CH 256              // db points staged per block (== ndb/NSPLIT)

// ---------------------------------------------------------------------------
__global__ void init_kernel(unsigned* __restrict__ mb, int n,
                            unsigned long long* __restrict__ acc) {
    int i = blockIdx.x * blockDim.x + threadIdx.x;
    if (i < n) mb[i] = 0x7f800000u;   // +inf
    if (i == 0) *acc = 0ull;
}

// ---------------------------------------------------------------------------
// minpass: expansion form  d2 = |p|^2 + (|t|^2 - 2 p.t)
// Query regs hold (-2px,-2py,-2pz) packed 2 queries per VGPR pair.
// LDS stages (tx,ty,tz,|t|^2) per db point; v_pk_fma_f32 op_sel broadcasts
// the point to both packed halves; v_min3_f32 merges 2 points per op.
// blockIdx.z: 0 = pred->target, 1 = target->pred.
// ---------------------------------------------------------------------------
__global__ void __launch_bounds__(TPB, 2) minpass(
    const float* __restrict__ pred, const float* __restrict__ target,
    unsigned* __restrict__ m1, unsigned* __restrict__ m2,
    int N, int M)
{
    const int pass = blockIdx.z;
    const float* __restrict__ q  = pass ? target : pred;
    const float* __restrict__ db = pass ? pred   : target;
    unsigned* __restrict__ minbits = pass ? m2 : m1;
    const int nq  = pass ? M : N;
    const int ndb = pass ? N : M;

    __shared__ v4f st[CH];

    const int tilesPerB = nq / (TPB * PTS);          // 2
    const int b    = blockIdx.x / tilesPerB;
    const int tile = blockIdx.x % tilesPerB;
    const int nbase = tile * (TPB * PTS) + threadIdx.x;

    v2f qx[QP], qy[QP], qz[QP];
    float mn[PTS];
#pragma unroll
    for (int i = 0; i < QP; ++i) {
        const float* q0 = q + ((size_t)b * nq + nbase + (2 * i) * TPB) * 3;
        const float* q1 = q + ((size_t)b * nq + nbase + (2 * i + 1) * TPB) * 3;
        v2f tx, ty, tz;
        tx.x = -2.0f * q0[0]; tx.y = -2.0f * q1[0];
        ty.x = -2.0f * q0[1]; ty.y = -2.0f * q1[1];
        tz.x = -2.0f * q0[2]; tz.y = -2.0f * q1[2];
        qx[i] = tx; qy[i] = ty; qz[i] = tz;
        mn[2 * i] = 3.4e38f; mn[2 * i + 1] = 3.4e38f;
    }

    // stage CH db points: one per thread
    {
        const float* dp = db + ((size_t)b * ndb + blockIdx.y * CH + threadIdx.x) * 3;
        const float x = dp[0], y = dp[1], z = dp[2];
        v4f t; t.x = x; t.y = y; t.z = z; t.w = fmaf(x, x, fmaf(y, y, z * z));
        st[threadIdx.x] = t;
    }
    __syncthreads();

#pragma unroll 4
    for (int j = 0; j < CH; j += 2) {
        const v4f ta = st[j];
        const v4f tb = st[j + 1];
        const v2f taxy = ta.xy, tazw = ta.zw;
        const v2f tbxy = tb.xy, tbzw = tb.zw;
#pragma unroll
        for (int i = 0; i < QP; ++i) {
            v2f ea, eb;
            // e = qz * tz + tw   (tz = lo of tzw bcast, tw = hi of tzw bcast)
            asm("v_pk_fma_f32 %0, %1, %2, %2 op_sel:[0,0,1] op_sel_hi:[1,0,1]"
                : "=v"(ea) : "v"(qz[i]), "v"(tazw));
            asm("v_pk_fma_f32 %0, %1, %2, %2 op_sel:[0,0,1] op_sel_hi:[1,0,1]"
                : "=v"(eb) : "v"(qz[i]), "v"(tbzw));
            // e += qy * ty       (ty = hi of txy bcast)
            asm("v_pk_fma_f32 %0, %1, %2, %0 op_sel:[0,1,0] op_sel_hi:[1,1,1]"
                : "+v"(ea) : "v"(qy[i]), "v"(taxy));
            asm("v_pk_fma_f32 %0, %1, %2, %0 op_sel:[0,1,0] op_sel_hi:[1,1,1]"
                : "+v"(eb) : "v"(qy[i]), "v"(tbxy));
            // e += qx * tx       (tx = lo of txy bcast)
            asm("v_pk_fma_f32 %0, %1, %2, %0 op_sel:[0,0,0] op_sel_hi:[1,0,1]"
                : "+v"(ea) : "v"(qx[i]), "v"(taxy));
            asm("v_pk_fma_f32 %0, %1, %2, %0 op_sel:[0,0,0] op_sel_hi:[1,0,1]"
                : "+v"(eb) : "v"(qx[i]), "v"(tbxy));
            // mn = min(ea, eb, mn) per query
            float ea0 = ea.x, ea1 = ea.y, eb0 = eb.x, eb1 = eb.y;
            asm("v_min3_f32 %0, %1, %2, %0" : "+v"(mn[2 * i])     : "v"(ea0), "v"(eb0));
            asm("v_min3_f32 %0, %1, %2, %0" : "+v"(mn[2 * i + 1]) : "v"(ea1), "v"(eb1));
        }
    }

#pragma unroll
    for (int i = 0; i < QP; ++i) {
        const v2f tx = qx[i], ty = qy[i], tz = qz[i];
        const float xn0 = 0.25f * fmaf(tx.x, tx.x, fmaf(ty.x, ty.x, tz.x * tz.x));
        const float xn1 = 0.25f * fmaf(tx.y, tx.y, fmaf(ty.y, ty.y, tz.y * tz.y));
        const float d0 = fmaxf(xn0 + mn[2 * i], 0.0f);
        const float d1 = fmaxf(xn1 + mn[2 * i + 1], 0.0f);
        atomicMin(&minbits[(size_t)b * nq + nbase + (2 * i) * TPB], __float_as_uint(d0));
        atomicMin(&minbits[(size_t)b * nq + nbase + (2 * i + 1) * TPB], __float_as_uint(d1));
    }
}

// ---------------------------------------------------------------------------
// reduce: parallel sqrt+sum of all min entries; deterministic via fixed-point
// u64 atomic accumulation (order-independent integer adds).
// ---------------------------------------------------------------------------
#define FIXSCALE 1099511627776.0   // 2^40

__global__ void __launch_bounds__(256) reduce_kernel(
    const unsigned* __restrict__ mall, int total, float inv,
    unsigned long long* __restrict__ acc)
{
    float s = 0.0f;
    for (int i = blockIdx.x * 256 + threadIdx.x; i < total; i += gridDim.x * 256)
        s += sqrtf(__uint_as_float(mall[i])) * inv;
    for (int off = 32; off; off >>= 1) s += __shfl_down(s, off, 64);
    __shared__ float ws[4];
    if ((threadIdx.x & 63) == 0) ws[threadIdx.x >> 6] = s;
    __syncthreads();
    if (threadIdx.x == 0) {
        const float t = ws[0] + ws[1] + ws[2] + ws[3];
        atomicAdd(acc, (unsigned long long)((double)t * FIXSCALE));
    }
}

__global__ void writeout(const unsigned long long* __restrict__ acc,
                         float* __restrict__ out) {
    out[0] = (float)((double)(*acc) * (1.0 / FIXSCALE));
}

// ---------------------------------------------------------------------------
extern "C" void kernel_launch(void* const* d_in, const int* in_sizes, int n_in,
                              void* d_out, int out_size, void* d_ws, size_t ws_size,
                              hipStream_t stream) {
    const float* pred   = (const float*)d_in[0];   // [B,N,3]
    const float* target = (const float*)d_in[1];   // [B,M,3]
    float* out = (float*)d_out;

    const int B = 4, N = 8192, M = 8192;

    unsigned* m1 = (unsigned*)d_ws;                       // [B*N]
    unsigned* m2 = m1 + (size_t)B * N;                    // [B*M]
    unsigned long long* acc =
        (unsigned long long*)(m1 + (size_t)B * (N + M));  // 8B, aligned

    const int tot = B * (N + M);                          // 65536
    init_kernel<<<tot / 256, 256, 0, stream>>>(m1, tot, acc);

    dim3 g(B * N / (TPB * PTS), NSPLIT, 2);               // (8, 32, 2)
    minpass<<<g, TPB, 0, stream>>>(pred, target, m1, m2, N, M);

    reduce_kernel<<<64, 256, 0, stream>>>(m1, tot, 1.0f / (B * N), acc);

    writeout<<<1, 64, 0, stream>>>(acc, out);
}

// Round 4
// 39.904 us; speedup vs baseline: 2.5783x; 1.3450x over previous
//
#include <hip/hip_runtime.h>

typedef short s16x8 __attribute__((ext_vector_type(8)));
typedef unsigned short u16x8 __attribute__((ext_vector_type(8)));
typedef float f32x16 __attribute__((ext_vector_type(16)));

#define MIN3(a,b,c) fminf(fminf((a),(b)),(c))

// bf16 round-to-nearest-even helpers
__device__ __forceinline__ unsigned short rne(float f) {
    unsigned u = __float_as_uint(f);
    return (unsigned short)((u + 0x7fffu + ((u >> 16) & 1u)) >> 16);
}
__device__ __forceinline__ float b2f(unsigned short b) {
    return __uint_as_float(((unsigned)b) << 16);
}

// ---------------------------------------------------------------------------
// preproc: per point build two 16-slot bf16 K-vectors (query-role A, db-role B)
//   d2 = |p|^2 + |t|^2 - 2 p.t  via one mfma_32x32x16 dot over K=16:
//   Q: [h(3), l(3), h(3), nh, nl, 1, 1, l(3)]
//   D: [-2h(3), -2h(3), -2l(3), 1, 1, nh, nl, -2l(3)]
// Layout per 32-point tile: [half(2)][point(32)][slot(8)] bf16  (1 KiB/tile)
// so lane l reads its 16B fragment at byte offset l*16.
// ---------------------------------------------------------------------------
__global__ void __launch_bounds__(256) preproc(
    const float* __restrict__ pred, const float* __restrict__ tgt,
    unsigned short* __restrict__ encQp, unsigned short* __restrict__ encQt,
    unsigned short* __restrict__ encDp, unsigned short* __restrict__ encDt)
{
    const int pid = blockIdx.x * 256 + threadIdx.x;       // [0, 32768)
    const float* __restrict__ src = blockIdx.y ? tgt : pred;
    unsigned short* __restrict__ encQ = blockIdx.y ? encQt : encQp;
    unsigned short* __restrict__ encD = blockIdx.y ? encDt : encDp;

    const float x = src[pid * 3], y = src[pid * 3 + 1], z = src[pid * 3 + 2];
    const int b = pid >> 13, i = pid & 8191, tile = i >> 5, pt = i & 31;

    const unsigned short hx = rne(x), hy = rne(y), hz = rne(z);
    const float fx = b2f(hx), fy = b2f(hy), fz = b2f(hz);
    const unsigned short lx = rne(x - fx), ly = rne(y - fy), lz = rne(z - fz);
    const float n = fmaf(x, x, fmaf(y, y, z * z));
    const unsigned short nh = rne(n);
    const unsigned short nl = rne(n - b2f(nh));
    const unsigned short one = 0x3f80;
    const unsigned short m2hx = rne(-2.0f * fx), m2hy = rne(-2.0f * fy), m2hz = rne(-2.0f * fz);
    const unsigned short m2lx = rne(-2.0f * b2f(lx)), m2ly = rne(-2.0f * b2f(ly)), m2lz = rne(-2.0f * b2f(lz));

    const size_t base = ((size_t)(b * 256 + tile)) * 512 + pt * 8;   // ushort idx

    u16x8 qlo, qhi, dlo, dhi;
    qlo[0]=hx; qlo[1]=hy; qlo[2]=hz; qlo[3]=lx; qlo[4]=ly; qlo[5]=lz; qlo[6]=hx; qlo[7]=hy;
    qhi[0]=hz; qhi[1]=nh; qhi[2]=nl; qhi[3]=one; qhi[4]=one; qhi[5]=lx; qhi[6]=ly; qhi[7]=lz;
    dlo[0]=m2hx; dlo[1]=m2hy; dlo[2]=m2hz; dlo[3]=m2hx; dlo[4]=m2hy; dlo[5]=m2hz; dlo[6]=m2lx; dlo[7]=m2ly;
    dhi[0]=m2lz; dhi[1]=one; dhi[2]=one; dhi[3]=nh; dhi[4]=nl; dhi[5]=m2lx; dhi[6]=m2ly; dhi[7]=m2lz;

    *(u16x8*)(encQ + base)       = qlo;
    *(u16x8*)(encQ + base + 256) = qhi;
    *(u16x8*)(encD + base)       = dlo;
    *(u16x8*)(encD + base + 256) = dhi;
}

// ---------------------------------------------------------------------------
__global__ void init_kernel(unsigned* __restrict__ mb, int n,
                            unsigned long long* __restrict__ acc) {
    int i = blockIdx.x * blockDim.x + threadIdx.x;
    if (i < n) mb[i] = 0x7f800000u;   // +inf
    if (i == 0) *acc = 0ull;
}

// ---------------------------------------------------------------------------
// minpass: D[db_row][query_col] = mfma(db_frag, query_frag, 0).
// Per lane: col = lane&31 (query), 16 regs span 16 db rows (of its lane>>5
// half) -> min over db = min3 tree over regs, then shfl_xor(32) merges halves.
// 4 query tiles per wave (A reuse), db chunk of 32 tiles staged in LDS once.
// ---------------------------------------------------------------------------
__global__ void __launch_bounds__(256) minpass(
    const unsigned short* __restrict__ encQp, const unsigned short* __restrict__ encQt,
    const unsigned short* __restrict__ encDp, const unsigned short* __restrict__ encDt,
    unsigned* __restrict__ m1, unsigned* __restrict__ m2)
{
    __shared__ unsigned short sdb[32 * 512];   // 32 tiles x 1 KiB = 32 KiB

    const int bid = blockIdx.x;
    const int pass = bid >> 9, b = (bid >> 7) & 3, split = (bid >> 4) & 7, qg = bid & 15;
    const unsigned short* __restrict__ encQ = pass ? encQt : encQp;
    const unsigned short* __restrict__ encD = pass ? encDp : encDt;
    unsigned* __restrict__ mout = pass ? m2 : m1;
    const int tid = threadIdx.x, lane = tid & 63, wid = tid >> 6;

    // stage db chunk (split*32 .. +31 tiles) into LDS
    {
        const int4* __restrict__ s = (const int4*)(encD + ((size_t)(b * 256 + split * 32)) * 512);
        int4* d = (int4*)sdb;
#pragma unroll
        for (int it = 0; it < 8; ++it) d[tid + it * 256] = s[tid + it * 256];
    }

    // query fragments: 4 tiles per wave, register-resident
    const int tbase = qg * 16 + wid * 4;
    s16x8 aq0 = *((const s16x8*)(encQ + ((size_t)(b * 256 + tbase + 0)) * 512) + lane);
    s16x8 aq1 = *((const s16x8*)(encQ + ((size_t)(b * 256 + tbase + 1)) * 512) + lane);
    s16x8 aq2 = *((const s16x8*)(encQ + ((size_t)(b * 256 + tbase + 2)) * 512) + lane);
    s16x8 aq3 = *((const s16x8*)(encQ + ((size_t)(b * 256 + tbase + 3)) * 512) + lane);

    f32x16 zero;
#pragma unroll
    for (int i = 0; i < 16; ++i) zero[i] = 0.0f;

    float mn0 = 3.4e38f, mn1 = 3.4e38f, mn2 = 3.4e38f, mn3 = 3.4e38f;

    __syncthreads();

#define FOLD2(mn, a, c) { \
        float u0 = MIN3(a[0], a[1], a[2]); \
        float u1 = MIN3(a[3], a[4], a[5]); \
        float u2 = MIN3(a[6], a[7], a[8]); \
        float u3 = MIN3(a[9], a[10], a[11]); \
        float u4 = MIN3(a[12], a[13], a[14]); \
        float u5 = MIN3(a[15], c[0], c[1]); \
        float u6 = MIN3(c[2], c[3], c[4]); \
        float u7 = MIN3(c[5], c[6], c[7]); \
        float u8 = MIN3(c[8], c[9], c[10]); \
        float u9 = MIN3(c[11], c[12], c[13]); \
        float ua = fminf(c[14], c[15]); \
        float v0 = MIN3(u0, u1, u2); \
        float v1 = MIN3(u3, u4, u5); \
        float v2 = MIN3(u6, u7, u8); \
        float v3 = MIN3(u9, ua, (mn)); \
        (mn) = MIN3(MIN3(v0, v1, v2), v3, (mn)); \
    }

    for (int t = 0; t < 32; t += 2) {
        const s16x8 d0 = *((const s16x8*)(sdb + t * 512) + lane);
        const s16x8 d1 = *((const s16x8*)(sdb + t * 512 + 512) + lane);
        {
            f32x16 accA = __builtin_amdgcn_mfma_f32_32x32x16_bf16(d0, aq0, zero, 0, 0, 0);
            f32x16 accB = __builtin_amdgcn_mfma_f32_32x32x16_bf16(d1, aq0, zero, 0, 0, 0);
            FOLD2(mn0, accA, accB);
        }
        {
            f32x16 accA = __builtin_amdgcn_mfma_f32_32x32x16_bf16(d0, aq1, zero, 0, 0, 0);
            f32x16 accB = __builtin_amdgcn_mfma_f32_32x32x16_bf16(d1, aq1, zero, 0, 0, 0);
            FOLD2(mn1, accA, accB);
        }
        {
            f32x16 accA = __builtin_amdgcn_mfma_f32_32x32x16_bf16(d0, aq2, zero, 0, 0, 0);
            f32x16 accB = __builtin_amdgcn_mfma_f32_32x32x16_bf16(d1, aq2, zero, 0, 0, 0);
            FOLD2(mn2, accA, accB);
        }
        {
            f32x16 accA = __builtin_amdgcn_mfma_f32_32x32x16_bf16(d0, aq3, zero, 0, 0, 0);
            f32x16 accB = __builtin_amdgcn_mfma_f32_32x32x16_bf16(d1, aq3, zero, 0, 0, 0);
            FOLD2(mn3, accA, accB);
        }
    }

    // merge the two db-row halves (lane ^ 32), clamp, write
    mn0 = fmaxf(fminf(mn0, __shfl_xor(mn0, 32)), 0.0f);
    mn1 = fmaxf(fminf(mn1, __shfl_xor(mn1, 32)), 0.0f);
    mn2 = fmaxf(fminf(mn2, __shfl_xor(mn2, 32)), 0.0f);
    mn3 = fmaxf(fminf(mn3, __shfl_xor(mn3, 32)), 0.0f);

    if (lane < 32) {
        const size_t qb = ((size_t)b << 13) + (size_t)tbase * 32 + lane;
        atomicMin(&mout[qb],      __float_as_uint(mn0));
        atomicMin(&mout[qb + 32], __float_as_uint(mn1));
        atomicMin(&mout[qb + 64], __float_as_uint(mn2));
        atomicMin(&mout[qb + 96], __float_as_uint(mn3));
    }
}

// ---------------------------------------------------------------------------
#define FIXSCALE 1099511627776.0   // 2^40

__global__ void __launch_bounds__(256) reduce_kernel(
    const unsigned* __restrict__ mall, int total, float inv,
    unsigned long long* __restrict__ acc)
{
    float s = 0.0f;
    for (int i = blockIdx.x * 256 + threadIdx.x; i < total; i += gridDim.x * 256)
        s += sqrtf(__uint_as_float(mall[i])) * inv;
    for (int off = 32; off; off >>= 1) s += __shfl_down(s, off, 64);
    __shared__ float ws[4];
    if ((threadIdx.x & 63) == 0) ws[threadIdx.x >> 6] = s;
    __syncthreads();
    if (threadIdx.x == 0) {
        const float t = ws[0] + ws[1] + ws[2] + ws[3];
        atomicAdd(acc, (unsigned long long)((double)t * FIXSCALE));
    }
}

__global__ void writeout(const unsigned long long* __restrict__ acc,
                         float* __restrict__ out) {
    out[0] = (float)((double)(*acc) * (1.0 / FIXSCALE));
}

// ---------------------------------------------------------------------------
extern "C" void kernel_launch(void* const* d_in, const int* in_sizes, int n_in,
                              void* d_out, int out_size, void* d_ws, size_t ws_size,
                              hipStream_t stream) {
    const float* pred   = (const float*)d_in[0];   // [4,8192,3]
    const float* target = (const float*)d_in[1];   // [4,8192,3]
    float* out = (float*)d_out;

    unsigned short* encQp = (unsigned short*)d_ws;          // 1 MiB each
    unsigned short* encQt = encQp + 524288;
    unsigned short* encDp = encQp + 2 * 524288;
    unsigned short* encDt = encQp + 3 * 524288;
    unsigned* m1 = (unsigned*)((char*)d_ws + 4u * 1048576u);  // 32768 u32
    unsigned* m2 = m1 + 32768;
    unsigned long long* acc = (unsigned long long*)(m2 + 32768);

    dim3 gp(128, 2);
    preproc<<<gp, 256, 0, stream>>>(pred, target, encQp, encQt, encDp, encDt);

    init_kernel<<<256, 256, 0, stream>>>(m1, 65536, acc);

    minpass<<<1024, 256, 0, stream>>>(encQp, encQt, encDp, encDt, m1, m2);

    reduce_kernel<<<64, 256, 0, stream>>>(m1, 65536, 1.0f / 32768.0f, acc);

    writeout<<<1, 64, 0, stream>>>(acc, out);
}

// Round 5
// 34.857 us; speedup vs baseline: 2.9517x; 1.1448x over previous
//
#include <hip/hip_runtime.h>

typedef short s16x8 __attribute__((ext_vector_type(8)));
typedef float f32x16 __attribute__((ext_vector_type(16)));

#define MIN3(a,b,c) fminf(fminf((a),(b)),(c))

// bf16 round-to-nearest-even helpers
__device__ __forceinline__ unsigned short rne(float f) {
    unsigned u = __float_as_uint(f);
    return (unsigned short)((u + 0x7fffu + ((u >> 16) & 1u)) >> 16);
}
__device__ __forceinline__ float b2f(unsigned short b) {
    return __uint_as_float(((unsigned)b) << 16);
}

// 16-slot hi/lo-split encoding (validated round 4, absmax 0):
//   slot pairing Q[s]*D[s] summed over K=16 gives
//   d2 = |q|^2 + |t|^2 - 2 (qh+ql).(th+tl)
// Q: lo=[hx,hy,hz,lx,ly,lz,hx,hy]  hi=[hz,nh,nl,1,1,lx,ly,lz]
// D: lo=[-2hx,-2hy,-2hz,-2hx,-2hy,-2hz,-2lx,-2ly] hi=[-2lz,1,1,nh,nl,-2lx,-2ly,-2lz]
__device__ __forceinline__ void encD(float x, float y, float z, s16x8& lo, s16x8& hi) {
    const unsigned short hx = rne(x), hy = rne(y), hz = rne(z);
    const float fx = b2f(hx), fy = b2f(hy), fz = b2f(hz);
    const unsigned short lx = rne(x - fx), ly = rne(y - fy), lz = rne(z - fz);
    const float n = fmaf(x, x, fmaf(y, y, z * z));
    const unsigned short nh = rne(n), nl = rne(n - b2f(nh));
    const unsigned short m2hx = rne(-2.f * fx), m2hy = rne(-2.f * fy), m2hz = rne(-2.f * fz);
    const unsigned short m2lx = rne(-2.f * b2f(lx)), m2ly = rne(-2.f * b2f(ly)), m2lz = rne(-2.f * b2f(lz));
    lo[0]=(short)m2hx; lo[1]=(short)m2hy; lo[2]=(short)m2hz; lo[3]=(short)m2hx;
    lo[4]=(short)m2hy; lo[5]=(short)m2hz; lo[6]=(short)m2lx; lo[7]=(short)m2ly;
    hi[0]=(short)m2lz; hi[1]=(short)0x3f80; hi[2]=(short)0x3f80; hi[3]=(short)nh;
    hi[4]=(short)nl;   hi[5]=(short)m2lx;  hi[6]=(short)m2ly;   hi[7]=(short)m2lz;
}

__device__ __forceinline__ s16x8 encQ(float x, float y, float z, int h) {
    const unsigned short hx = rne(x), hy = rne(y), hz = rne(z);
    const float fx = b2f(hx), fy = b2f(hy), fz = b2f(hz);
    const unsigned short lx = rne(x - fx), ly = rne(y - fy), lz = rne(z - fz);
    const float n = fmaf(x, x, fmaf(y, y, z * z));
    const unsigned short nh = rne(n), nl = rne(n - b2f(nh));
    s16x8 lo, hiV;
    lo[0]=(short)hx; lo[1]=(short)hy; lo[2]=(short)hz; lo[3]=(short)lx;
    lo[4]=(short)ly; lo[5]=(short)lz; lo[6]=(short)hx; lo[7]=(short)hy;
    hiV[0]=(short)hz; hiV[1]=(short)nh; hiV[2]=(short)nl; hiV[3]=(short)0x3f80;
    hiV[4]=(short)0x3f80; hiV[5]=(short)lx; hiV[6]=(short)ly; hiV[7]=(short)lz;
    return h ? hiV : lo;
}

// ---------------------------------------------------------------------------
__global__ void __launch_bounds__(256) init_kernel(
    unsigned* __restrict__ mb, unsigned long long* __restrict__ acc,
    unsigned* __restrict__ ticket)
{
    const int i = blockIdx.x * 256 + threadIdx.x;
    mb[i] = 0x7f800000u;   // +inf
    if (i == 0) { *acc = 0ull; *ticket = 0u; }
}

// ---------------------------------------------------------------------------
// minpass (fused encode): bid fields qg(32) | split(16) | b(4) | pass(2).
// Block: stages+encodes 512 db points (16 tiles, 16 KiB LDS); each of 4 waves
// owns 2 query tiles (register A-frags). mfma(db, query): lane's 16 acc regs
// span 16 db rows of its half -> min3 tree, shfl_xor(32), atomicMin.
// launch_bounds(256,4): cap VGPR<=128 to forbid acc-hoist spills.
// ---------------------------------------------------------------------------
__global__ void __launch_bounds__(256, 4) minpass(
    const float* __restrict__ pred, const float* __restrict__ tgt,
    unsigned* __restrict__ m1, unsigned* __restrict__ m2)
{
    __shared__ s16x8 sdb[16 * 64];   // [tile][half*32+pt], 16 KiB

    const int bid = blockIdx.x;
    const int qg = bid & 31, split = (bid >> 5) & 15, b = (bid >> 9) & 3, pass = bid >> 11;
    const float* __restrict__ q  = pass ? tgt : pred;
    const float* __restrict__ db = pass ? pred : tgt;
    unsigned* __restrict__ mout = pass ? m2 : m1;

    const int tid = threadIdx.x, lane = tid & 63, wid = tid >> 6;

    // stage & encode db chunk: points tid and tid+256 (16B-stride LDS writes)
    {
        const float* dp = db + ((size_t)b * 8192 + split * 512 + tid) * 3;
        s16x8 lo, hi;
        encD(dp[0], dp[1], dp[2], lo, hi);
        sdb[(tid >> 5) * 64 + (tid & 31)] = lo;
        sdb[(tid >> 5) * 64 + 32 + (tid & 31)] = hi;
        const float* dp2 = dp + 768;
        encD(dp2[0], dp2[1], dp2[2], lo, hi);
        const int p = tid + 256;
        sdb[(p >> 5) * 64 + (p & 31)] = lo;
        sdb[(p >> 5) * 64 + 32 + (p & 31)] = hi;
    }

    // query fragments: 2 tiles per wave, encoded in-register
    const int tq = qg * 8 + wid * 2;
    const int h = lane >> 5;
    const float* qp = q + ((size_t)b * 8192 + tq * 32 + (lane & 31)) * 3;
    const s16x8 aq0 = encQ(qp[0], qp[1], qp[2], h);
    const s16x8 aq1 = encQ(qp[96], qp[97], qp[98], h);

    f32x16 zerov;
#pragma unroll
    for (int i = 0; i < 16; ++i) zerov[i] = 0.0f;

    float mn0 = 3.4e38f, mn1 = 3.4e38f;

    __syncthreads();

#define FOLD2(mn, a, c) { \
        float u0 = MIN3(a[0], a[1], a[2]); \
        float u1 = MIN3(a[3], a[4], a[5]); \
        float u2 = MIN3(a[6], a[7], a[8]); \
        float u3 = MIN3(a[9], a[10], a[11]); \
        float u4 = MIN3(a[12], a[13], a[14]); \
        float u5 = MIN3(a[15], c[0], c[1]); \
        float u6 = MIN3(c[2], c[3], c[4]); \
        float u7 = MIN3(c[5], c[6], c[7]); \
        float u8 = MIN3(c[8], c[9], c[10]); \
        float u9 = MIN3(c[11], c[12], c[13]); \
        float ua = fminf(c[14], c[15]); \
        float v0 = MIN3(u0, u1, u2); \
        float v1 = MIN3(u3, u4, u5); \
        float v2 = MIN3(u6, u7, u8); \
        float v3 = MIN3(u9, ua, (mn)); \
        (mn) = fminf(MIN3(v0, v1, v2), v3); \
    }

#pragma unroll 2
    for (int t = 0; t < 16; t += 2) {
        const s16x8 d0 = sdb[t * 64 + lane];
        const s16x8 d1 = sdb[t * 64 + 64 + lane];
        {
            f32x16 accA = __builtin_amdgcn_mfma_f32_32x32x16_bf16(d0, aq0, zerov, 0, 0, 0);
            f32x16 accB = __builtin_amdgcn_mfma_f32_32x32x16_bf16(d1, aq0, zerov, 0, 0, 0);
            FOLD2(mn0, accA, accB);
        }
        {
            f32x16 accA = __builtin_amdgcn_mfma_f32_32x32x16_bf16(d0, aq1, zerov, 0, 0, 0);
            f32x16 accB = __builtin_amdgcn_mfma_f32_32x32x16_bf16(d1, aq1, zerov, 0, 0, 0);
            FOLD2(mn1, accA, accB);
        }
    }

    mn0 = fmaxf(fminf(mn0, __shfl_xor(mn0, 32)), 0.0f);
    mn1 = fmaxf(fminf(mn1, __shfl_xor(mn1, 32)), 0.0f);

    if (lane < 32) {
        const size_t qb = ((size_t)b << 13) + (size_t)tq * 32 + lane;
        atomicMin(&mout[qb],      __float_as_uint(mn0));
        atomicMin(&mout[qb + 32], __float_as_uint(mn1));
    }
}

// ---------------------------------------------------------------------------
// reduce + writeout: fixed-point u64 accumulation (order-independent ->
// deterministic); last-ticket block writes the scalar.
// ---------------------------------------------------------------------------
#define FIXSCALE 1099511627776.0   // 2^40
#define RBLOCKS 64

__global__ void __launch_bounds__(256) reduce_writeout(
    const unsigned* __restrict__ mall, unsigned long long* __restrict__ acc,
    unsigned* __restrict__ ticket, float* __restrict__ out)
{
    float s = 0.0f;
    for (int i = blockIdx.x * 256 + threadIdx.x; i < 65536; i += RBLOCKS * 256)
        s += sqrtf(__uint_as_float(mall[i]));
    for (int off = 32; off; off >>= 1) s += __shfl_down(s, off, 64);
    __shared__ float ws[4];
    if ((threadIdx.x & 63) == 0) ws[threadIdx.x >> 6] = s;
    __syncthreads();
    if (threadIdx.x == 0) {
        const double t = (double)(ws[0] + ws[1] + ws[2] + ws[3]) * (1.0 / 32768.0);
        atomicAdd(acc, (unsigned long long)(t * FIXSCALE));
        __threadfence();
        const unsigned tk = atomicAdd(ticket, 1u);
        if (tk == RBLOCKS - 1) {
            const unsigned long long v = atomicAdd(acc, 0ull);
            out[0] = (float)((double)v * (1.0 / FIXSCALE));
        }
    }
}

// ---------------------------------------------------------------------------
extern "C" void kernel_launch(void* const* d_in, const int* in_sizes, int n_in,
                              void* d_out, int out_size, void* d_ws, size_t ws_size,
                              hipStream_t stream) {
    const float* pred   = (const float*)d_in[0];   // [4,8192,3]
    const float* target = (const float*)d_in[1];   // [4,8192,3]
    float* out = (float*)d_out;

    unsigned* m1 = (unsigned*)d_ws;                       // [32768] pred mins
    unsigned* m2 = m1 + 32768;                            // [32768] target mins
    unsigned long long* acc = (unsigned long long*)(m2 + 32768);
    unsigned* ticket = (unsigned*)(acc + 1);

    init_kernel<<<256, 256, 0, stream>>>(m1, acc, ticket);

    minpass<<<4096, 256, 0, stream>>>(pred, target, m1, m2);

    reduce_writeout<<<RBLOCKS, 256, 0, stream>>>(m1, acc, ticket, out);
}